// Round 8
// baseline (97.285 us; speedup 1.0000x reference)
//
#include <hip/hip_runtime.h>

#define Bb 64
#define Ll 32
#define Hh 128
#define Oo 16384
#define Cc 32

// ws (floats): A[8192] | SA2w[64] | w2h[128] | w1t[4096] | gcoef[256] | pad | g_t[Hh*Oo]

// ---------------------------------------------------------------------------
// prep: A = relu(z@Wz+bz)@W1[:H];  SA2w[b] = sum 0.5*W2*A[b,:] + b2
// side: w1t = W1_f^T (h-major), w2h = 0.5*W2, gcoef[h] = {w1b[h], b1[h]}
// ---------------------------------------------------------------------------
__global__ __launch_bounds__(256) void prep_kernel(
    const float* __restrict__ z, const float* __restrict__ Wz,
    const float* __restrict__ bz, const float* __restrict__ W1,
    const float* __restrict__ b1, const float* __restrict__ W2,
    const float* __restrict__ b2,
    float* __restrict__ A, float* __restrict__ SA2w,
    float* __restrict__ w2h, float* __restrict__ w1t,
    float* __restrict__ gcoef)
{
    __shared__ float pz[2][Hh];
    __shared__ float ps[2][Hh];
    const int t  = threadIdx.x;
    const int h  = t & (Hh - 1);
    const int bb = t >> 7;
    const int b  = blockIdx.x * 2 + bb;

    float v = bz[h];
#pragma unroll
    for (int c = 0; c < Ll; ++c)
        v = fmaf(z[b * Ll + c], Wz[c * Hh + h], v);
    pz[bb][h] = fmaxf(v, 0.f);
    __syncthreads();

    float a = 0.f;
#pragma unroll
    for (int k = 0; k < Hh; ++k)
        a = fmaf(pz[bb][k], W1[k * Hh + h], a);
    A[b * Hh + h] = a;
    ps[bb][h] = 0.5f * W2[h] * a;
    __syncthreads();

    if (h == 0) {
        float s = b2[0];
        for (int k = 0; k < Hh; ++k) s += ps[bb][k];
        SA2w[b] = s;
    }

    // side work (each of 32 blocks handles 4 h-columns)
    if (t < 128) {
        const int h2 = blockIdx.x * 4 + (t >> 5);
        const int c  = t & 31;
        w1t[h2 * Cc + c] = W1[(Hh + c) * Hh + h2];
    }
    if (t < 4) {
        const int h2 = blockIdx.x * 4 + t;
        w2h[h2] = 0.5f * W2[h2];
        gcoef[2 * h2 + 0] = W1[(Hh + Cc) * Hh + h2];
        gcoef[2 * h2 + 1] = b1[h2];
    }
}

// ---------------------------------------------------------------------------
// g_kernel: g[o,h] = fe[o,:]@W1_f[:,h] + fb[o]*w1b[h] + b1[h]
// 512 blocks x 256 thr, NO LDS, NO sync. lane = o holds fe row in 32 VGPRs;
// w1t/gcoef via uniform s_load. Output layout: h-pair interleaved,
//   g_t[hp*2*Oo + 2*o + (h&1)]  -> consumer reads dwordx2 per (o, h-pair).
// Swizzle: oblk = bid&255, hblk = bid>>8 (stride-256 pairs share an XCD).
// ---------------------------------------------------------------------------
__global__ __launch_bounds__(256) void g_kernel(
    const float* __restrict__ fe, const float* __restrict__ fb,
    const float* __restrict__ w1t, const float* __restrict__ gcoef,
    float* __restrict__ g_t)
{
    const int t    = threadIdx.x;
    const int lane = t & 63;
    const int wave = __builtin_amdgcn_readfirstlane(t >> 6);
    const int o    = (blockIdx.x & 255) * 64 + lane;
    const int hb   = (blockIdx.x >> 8) * 64 + wave * 16;   // 16 h per wave

    float4 fer[8];
    const float4* fep = (const float4*)(fe + o * Cc);
#pragma unroll
    for (int k = 0; k < 8; ++k) fer[k] = fep[k];
    const float fbv = fb[o];

#pragma unroll 1
    for (int j = 0; j < 8; ++j) {                  // 2 h per iter
        const int h = hb + 2 * j;
        const float* __restrict__ wt0 = w1t + (h + 0) * Cc;   // uniform
        const float* __restrict__ wt1 = w1t + (h + 1) * Cc;   // uniform
        float g0 = fmaf(fbv, gcoef[2 * h + 0], gcoef[2 * h + 1]);
        float g1 = fmaf(fbv, gcoef[2 * h + 2], gcoef[2 * h + 3]);
#pragma unroll
        for (int k = 0; k < 8; ++k) {
            g0 = fmaf(fer[k].x, wt0[4 * k + 0], g0);
            g0 = fmaf(fer[k].y, wt0[4 * k + 1], g0);
            g0 = fmaf(fer[k].z, wt0[4 * k + 2], g0);
            g0 = fmaf(fer[k].w, wt0[4 * k + 3], g0);
            g1 = fmaf(fer[k].x, wt1[4 * k + 0], g1);
            g1 = fmaf(fer[k].y, wt1[4 * k + 1], g1);
            g1 = fmaf(fer[k].z, wt1[4 * k + 2], g1);
            g1 = fmaf(fer[k].w, wt1[4 * k + 3], g1);
        }
        const int hp = (hb >> 1) + j;
        *(float2*)(g_t + hp * (2 * Oo) + 2 * o) = make_float2(g0, g1);
    }
}

// ---------------------------------------------------------------------------
// m_kernel: out[b,o] = SA2w[b] + sum_h w2h[h]*g[o,h] + sum_h w2h[h]*|A[b,h]+g[o,h]|
//   (w*relu(x) = 0.5w*x + 0.5w*|x|, exact; b2 in SA2w)
// 1024 blocks x 256 thr (4/CU), NO LDS, NO sync, VGPR ~32 -> deep TLP.
// lane = o (coalesced g loads + stores); wave owns 4 b-rows (A/w2 via s_load).
// Swizzle: oblk = bid&255, bblk = bid>>8 -> the 4 b-replicas of an o-range
// land on the SAME XCD (RR dispatch, 256 % 8 == 0) so g stays L2-resident.
// ---------------------------------------------------------------------------
__global__ __launch_bounds__(256) void m_kernel(
    const float* __restrict__ A, const float* __restrict__ SA2w,
    const float* __restrict__ w2h, const float* __restrict__ g_t,
    float* __restrict__ out)
{
    const int t    = threadIdx.x;
    const int lane = t & 63;
    const int wave = __builtin_amdgcn_readfirstlane(t >> 6);
    const int o    = (blockIdx.x & 255) * 64 + lane;
    const int b0   = (blockIdx.x >> 8) * 16 + wave * 4;

    const float* __restrict__ A0 = A + (b0 + 0) * Hh;   // uniform rows
    const float* __restrict__ A1 = A + (b0 + 1) * Hh;
    const float* __restrict__ A2 = A + (b0 + 2) * Hh;
    const float* __restrict__ A3 = A + (b0 + 3) * Hh;

    float acc0 = 0.f, acc1 = 0.f, acc2 = 0.f, acc3 = 0.f, sg = 0.f;

#pragma unroll 1
    for (int hc = 0; hc < 16; ++hc) {              // 8 h per iter
        const int h0 = hc * 8;
        float g[8];
#pragma unroll
        for (int k = 0; k < 4; ++k) {              // coalesced dwordx2
            const float2 g2 = *(const float2*)(g_t + (4 * hc + k) * (2 * Oo) + 2 * o);
            g[2 * k + 0] = g2.x;
            g[2 * k + 1] = g2.y;
        }
#pragma unroll
        for (int j = 0; j < 8; ++j) {
            const int h = h0 + j;
            const float w = w2h[h];                // uniform -> s_load
            sg   = fmaf(w, g[j], sg);
            acc0 = fmaf(__builtin_fabsf(A0[h] + g[j]), w, acc0);
            acc1 = fmaf(__builtin_fabsf(A1[h] + g[j]), w, acc1);
            acc2 = fmaf(__builtin_fabsf(A2[h] + g[j]), w, acc2);
            acc3 = fmaf(__builtin_fabsf(A3[h] + g[j]), w, acc3);
        }
    }

    const float s0 = SA2w[b0 + 0], s1 = SA2w[b0 + 1];
    const float s2 = SA2w[b0 + 2], s3 = SA2w[b0 + 3];
    out[(b0 + 0) * Oo + o] = acc0 + sg + s0;       // coalesced 256B stores
    out[(b0 + 1) * Oo + o] = acc1 + sg + s1;
    out[(b0 + 2) * Oo + o] = acc2 + sg + s2;
    out[(b0 + 3) * Oo + o] = acc3 + sg + s3;
}

extern "C" void kernel_launch(void* const* d_in, const int* in_sizes, int n_in,
                              void* d_out, int out_size, void* d_ws, size_t ws_size,
                              hipStream_t stream) {
    (void)in_sizes; (void)n_in; (void)out_size; (void)ws_size;
    const float* z   = (const float*)d_in[0];   // (64,32)
    const float* fe  = (const float*)d_in[1];   // (16384,32)
    const float* fb  = (const float*)d_in[2];   // (16384,1)
    const float* Wz  = (const float*)d_in[3];   // (32,128)
    const float* bz  = (const float*)d_in[4];   // (128,)
    const float* W1  = (const float*)d_in[5];   // (161,128)
    const float* b1  = (const float*)d_in[6];   // (128,)
    const float* W2  = (const float*)d_in[7];   // (128,1)
    const float* b2  = (const float*)d_in[8];   // (1,)
    float* out   = (float*)d_out;               // (64,16384)
    float* A     = (float*)d_ws;                // 8192
    float* SA2w  = A + Bb * Hh;                 // 64
    float* w2h   = SA2w + Bb;                   // 128
    float* w1t   = w2h + Hh;                    // 4096
    float* gcoef = w1t + Hh * Cc;               // 256
    float* g_t   = (float*)d_ws + 16384;        // Hh*Oo = 2M floats, aligned

    prep_kernel<<<Bb / 2, 256, 0, stream>>>(z, Wz, bz, W1, b1, W2, b2,
                                            A, SA2w, w2h, w1t, gcoef);
    g_kernel<<<512, 256, 0, stream>>>(fe, fb, w1t, gcoef, g_t);
    m_kernel<<<1024, 256, 0, stream>>>(A, SA2w, w2h, g_t, out);
}